// Round 1
// baseline (162.792 us; speedup 1.0000x reference)
//
#include <hip/hip_runtime.h>
#include <hip/hip_bf16.h>
#include <cstddef>

// Problem constants (match reference)
static constexpr int Bdim = 32;
static constexpr int Edim = 256;
static constexpr int Cdim = 7;
static constexpr int Ddim = 256;

// Precomputed fused tables, 101 rows of 256 floats:
// rows  0..52 : cardP  = card_table   @ Wc[   0: 256]
// rows 53..61 : heroP  = hero_table   @ Wc[ 256: 512]
// rows 62..70 : actP   = acting_table @ Wc[ 512: 768]
// rows 71..80 : numP   = nump_table   @ Wc[ 768:1024]
// rows 81..82 : WsP    = W_scalar     @ Wc[1024:1280]
// rows 83..91 : WbP    = W_bet        @ Wc[1280:1536]
// rows 92..99 : WaP    = W_action     @ Wc[1536:1792]
// row  100    : bP     = b_combine + b_scalar@Wc4 + b_bet@Wc5 + b_action@Wc6
__device__ float g_tabs[101 * Ddim];

__global__ __launch_bounds__(256) void precompute_tables(
    const float* __restrict__ card_table,
    const float* __restrict__ hero_table,
    const float* __restrict__ acting_table,
    const float* __restrict__ nump_table,
    const float* __restrict__ W_scalar, const float* __restrict__ b_scalar,
    const float* __restrict__ W_bet,    const float* __restrict__ b_bet,
    const float* __restrict__ W_action, const float* __restrict__ b_action,
    const float* __restrict__ W_combine, const float* __restrict__ b_combine)
{
    __shared__ float src[Ddim];
    const int r = blockIdx.x;
    const int d = threadIdx.x;
    float acc = 0.0f;

    if (r < 100) {
        const float* srcp;
        int off;
        if      (r < 53) { srcp = card_table   + (size_t)r        * Ddim; off = 0;    }
        else if (r < 62) { srcp = hero_table   + (size_t)(r - 53) * Ddim; off = 256;  }
        else if (r < 71) { srcp = acting_table + (size_t)(r - 62) * Ddim; off = 512;  }
        else if (r < 81) { srcp = nump_table   + (size_t)(r - 71) * Ddim; off = 768;  }
        else if (r < 83) { srcp = W_scalar     + (size_t)(r - 81) * Ddim; off = 1024; }
        else if (r < 92) { srcp = W_bet        + (size_t)(r - 83) * Ddim; off = 1280; }
        else             { srcp = W_action     + (size_t)(r - 92) * Ddim; off = 1536; }
        src[d] = srcp[d];
        __syncthreads();
        const float* w = W_combine + (size_t)off * Ddim + d;
        #pragma unroll 4
        for (int k = 0; k < Ddim; ++k)
            acc = fmaf(src[k], w[(size_t)k * Ddim], acc);
    } else {
        // fused bias row: push b_scalar/b_bet/b_action through their Wc slices
        const int   offs[3] = {1024, 1280, 1536};
        const float* bias[3] = {b_scalar, b_bet, b_action};
        for (int t = 0; t < 3; ++t) {
            __syncthreads();
            src[d] = bias[t][d];
            __syncthreads();
            const float* w = W_combine + (size_t)offs[t] * Ddim + d;
            #pragma unroll 4
            for (int k = 0; k < Ddim; ++k)
                acc = fmaf(src[k], w[(size_t)k * Ddim], acc);
        }
        acc += b_combine[d];
    }
    g_tabs[(size_t)r * Ddim + d] = acc;
}

__device__ __forceinline__ float4 ld4(const float* p) {
    return *reinterpret_cast<const float4*>(p);
}
__device__ __forceinline__ void add4(float4& a, const float4 b) {
    a.x += b.x; a.y += b.y; a.z += b.z; a.w += b.w;
}
__device__ __forceinline__ void fma4(float4& a, const float s, const float4 b) {
    a.x = fmaf(s, b.x, a.x);
    a.y = fmaf(s, b.y, a.y);
    a.z = fmaf(s, b.z, a.z);
    a.w = fmaf(s, b.w, a.w);
}

// One wave (64 lanes) per event; lane holds d = 4*lane .. 4*lane+3 as float4.
// 4 waves per 256-thread block -> grid = 8192/4 = 2048 blocks.
__global__ __launch_bounds__(256) void event_embed(
    const int* __restrict__ card_ids,
    const int* __restrict__ hero_pos,
    const int* __restrict__ acting_pos,
    const int* __restrict__ num_players,
    const int* __restrict__ seq_lengths,
    const float* __restrict__ scalars,
    const float* __restrict__ bets,
    const float* __restrict__ action,
    const float* __restrict__ source_table,
    const float* __restrict__ ln_gamma,
    const float* __restrict__ ln_beta,
    float* __restrict__ out_emb,
    float* __restrict__ out_mask)
{
    const int wave = threadIdx.x >> 6;
    const int lane = threadIdx.x & 63;
    const int g = (blockIdx.x << 2) + wave;   // event index in [0, B*E)
    const int b = g >> 8;                     // E = 256
    const int e = g & 255;
    const int d0 = lane << 2;

    const float* cardP = g_tabs;
    const float* heroP = cardP + 53 * Ddim;
    const float* actP  = heroP +  9 * Ddim;
    const float* numP  = actP  +  9 * Ddim;
    const float* WsP   = numP  + 10 * Ddim;
    const float* WbP   = WsP   +  2 * Ddim;
    const float* WaP   = WbP   +  9 * Ddim;
    const float* bP    = WaP   +  8 * Ddim;

    const float maskf = (e < seq_lengths[b]) ? 1.0f : 0.0f;

    // context vector shared by the event's 7 cards
    float4 ctx = ld4(bP + d0);
    add4(ctx, ld4(heroP + (size_t)hero_pos[g]    * Ddim + d0));
    add4(ctx, ld4(actP  + (size_t)acting_pos[g]  * Ddim + d0));
    add4(ctx, ld4(numP  + (size_t)num_players[g] * Ddim + d0));
    fma4(ctx, scalars[(size_t)g * 2 + 0], ld4(WsP + d0));
    fma4(ctx, scalars[(size_t)g * 2 + 1], ld4(WsP + Ddim + d0));
    #pragma unroll
    for (int j = 0; j < 9; ++j)
        fma4(ctx, bets[(size_t)g * 9 + j], ld4(WbP + j * Ddim + d0));
    #pragma unroll
    for (int j = 0; j < 8; ++j)
        fma4(ctx, action[(size_t)g * 8 + j], ld4(WaP + j * Ddim + d0));

    const float4 gam = ld4(ln_gamma + d0);
    const float4 bta = ld4(ln_beta + d0);
    const float4 s0v = ld4(source_table + d0);          // source id 0 (cards 0..4)
    const float4 s1v = ld4(source_table + Ddim + d0);   // source id 1 (cards 5..6)

    #pragma unroll
    for (int c = 0; c < Cdim; ++c) {
        const int cid = card_ids[(size_t)g * Cdim + c];
        float4 h = ld4(cardP + (size_t)cid * Ddim + d0);
        add4(h, ctx);

        float s  = h.x + h.y + h.z + h.w;
        float sq = h.x * h.x + h.y * h.y + h.z * h.z + h.w * h.w;
        #pragma unroll
        for (int off = 32; off > 0; off >>= 1) {
            s  += __shfl_xor(s,  off, 64);
            sq += __shfl_xor(sq, off, 64);
        }
        const float mean = s * (1.0f / 256.0f);
        const float var  = fmaf(-mean, mean, sq * (1.0f / 256.0f));
        const float inv  = rsqrtf(var + 1e-5f);

        const float4 sv = (c < 5) ? s0v : s1v;
        float4 o;
        o.x = (fmaf((h.x - mean) * inv, gam.x, bta.x) + sv.x) * maskf;
        o.y = (fmaf((h.y - mean) * inv, gam.y, bta.y) + sv.y) * maskf;
        o.z = (fmaf((h.z - mean) * inv, gam.z, bta.z) + sv.z) * maskf;
        o.w = (fmaf((h.w - mean) * inv, gam.w, bta.w) + sv.w) * maskf;
        *reinterpret_cast<float4*>(out_emb + ((size_t)g * Cdim + c) * Ddim + d0) = o;
    }

    if (lane < Cdim)
        out_mask[(size_t)g * Cdim + lane] = maskf;
}

extern "C" void kernel_launch(void* const* d_in, const int* in_sizes, int n_in,
                              void* d_out, int out_size, void* d_ws, size_t ws_size,
                              hipStream_t stream)
{
    (void)in_sizes; (void)n_in; (void)d_ws; (void)ws_size; (void)out_size;

    const int*   card_ids    = (const int*)d_in[0];
    const int*   hero_pos    = (const int*)d_in[1];
    const int*   acting_pos  = (const int*)d_in[2];
    const int*   num_players = (const int*)d_in[3];
    const int*   seq_lengths = (const int*)d_in[4];
    const float* scalars     = (const float*)d_in[5];
    const float* bets        = (const float*)d_in[6];
    const float* action      = (const float*)d_in[7];
    const float* card_table  = (const float*)d_in[8];
    const float* source_tab  = (const float*)d_in[9];
    const float* hero_table  = (const float*)d_in[10];
    const float* acting_tab  = (const float*)d_in[11];
    const float* nump_table  = (const float*)d_in[12];
    const float* W_scalar    = (const float*)d_in[13];
    const float* b_scalar    = (const float*)d_in[14];
    const float* W_bet       = (const float*)d_in[15];
    const float* b_bet       = (const float*)d_in[16];
    const float* W_action    = (const float*)d_in[17];
    const float* b_action    = (const float*)d_in[18];
    const float* W_combine   = (const float*)d_in[19];
    const float* b_combine   = (const float*)d_in[20];
    const float* ln_gamma    = (const float*)d_in[21];
    const float* ln_beta     = (const float*)d_in[22];

    float* out_emb  = (float*)d_out;
    float* out_mask = out_emb + (size_t)Bdim * Edim * Cdim * Ddim;

    hipLaunchKernelGGL(precompute_tables, dim3(101), dim3(256), 0, stream,
                       card_table, hero_table, acting_tab, nump_table,
                       W_scalar, b_scalar, W_bet, b_bet, W_action, b_action,
                       W_combine, b_combine);

    const int nEvents = Bdim * Edim;             // 8192
    hipLaunchKernelGGL(event_embed, dim3(nEvents / 4), dim3(256), 0, stream,
                       card_ids, hero_pos, acting_pos, num_players, seq_lengths,
                       scalars, bets, action, source_tab, ln_gamma, ln_beta,
                       out_emb, out_mask);
}

// Round 2
// 135.491 us; speedup vs baseline: 1.2015x; 1.2015x over previous
//
#include <hip/hip_runtime.h>
#include <hip/hip_bf16.h>
#include <cstddef>

// Problem constants (match reference)
static constexpr int Bdim = 32;
static constexpr int Edim = 256;
static constexpr int Cdim = 7;
static constexpr int Ddim = 256;

// Precomputed fused tables, 101 rows of 256 floats:
// rows  0..52 : cardP  = card_table   @ Wc[   0: 256]
// rows 53..61 : heroP  = hero_table   @ Wc[ 256: 512]
// rows 62..70 : actP   = acting_table @ Wc[ 512: 768]
// rows 71..80 : numP   = nump_table   @ Wc[ 768:1024]
// rows 81..82 : WsP    = W_scalar     @ Wc[1024:1280]
// rows 83..91 : WbP    = W_bet        @ Wc[1280:1536]
// rows 92..99 : WaP    = W_action     @ Wc[1536:1792]
// row  100    : bP     = b_combine + b_scalar@Wc4 + b_bet@Wc5 + b_action@Wc6
__device__ float g_tabs[101 * Ddim];

// 1024 threads: thread = d (0..255) + 256*kc (kc = 0..3, K-split).
// Each thread computes a partial dot over its 64-element K chunk (fully
// unrolled -> many outstanding coalesced loads), then LDS tree-reduce the
// 4 partials per d. 101 blocks x 16 waves = 1616 waves -> latency hidden.
__global__ __launch_bounds__(1024) void precompute_tables(
    const float* __restrict__ card_table,
    const float* __restrict__ hero_table,
    const float* __restrict__ acting_table,
    const float* __restrict__ nump_table,
    const float* __restrict__ W_scalar, const float* __restrict__ b_scalar,
    const float* __restrict__ W_bet,    const float* __restrict__ b_bet,
    const float* __restrict__ W_action, const float* __restrict__ b_action,
    const float* __restrict__ W_combine, const float* __restrict__ b_combine)
{
    __shared__ float src[768];        // source row (256) or 3 bias rows (768)
    __shared__ float partial[1024];
    const int tid = threadIdx.x;
    const int r  = blockIdx.x;
    const int d  = tid & 255;
    const int kc = tid >> 8;          // 0..3
    float acc = 0.0f;

    if (r < 100) {
        const float* srcp;
        int off;
        if      (r < 53) { srcp = card_table   + (size_t)r        * Ddim; off = 0;    }
        else if (r < 62) { srcp = hero_table   + (size_t)(r - 53) * Ddim; off = 256;  }
        else if (r < 71) { srcp = acting_table + (size_t)(r - 62) * Ddim; off = 512;  }
        else if (r < 81) { srcp = nump_table   + (size_t)(r - 71) * Ddim; off = 768;  }
        else if (r < 83) { srcp = W_scalar     + (size_t)(r - 81) * Ddim; off = 1024; }
        else if (r < 92) { srcp = W_bet        + (size_t)(r - 83) * Ddim; off = 1280; }
        else             { srcp = W_action     + (size_t)(r - 92) * Ddim; off = 1536; }
        if (tid < 256) src[tid] = srcp[tid];
        __syncthreads();
        const int k0 = kc << 6;       // kc * 64
        const float* w = W_combine + ((size_t)off + k0) * Ddim + d;
        #pragma unroll
        for (int k = 0; k < 64; ++k)
            acc = fmaf(src[k0 + k], w[(size_t)k * Ddim], acc);
    } else {
        // fused bias row: concatenated K space q in [0,768):
        //   t = q>>8 selects {b_scalar,b_bet,b_action}; W row index = 1024+q.
        if      (tid < 256) src[tid] = b_scalar[tid];
        else if (tid < 512) src[tid] = b_bet[tid - 256];
        else if (tid < 768) src[tid] = b_action[tid - 512];
        __syncthreads();
        const int q0 = kc * 192;
        #pragma unroll 16
        for (int q = q0; q < q0 + 192; ++q)
            acc = fmaf(src[q], W_combine[(size_t)(1024 + q) * Ddim + d], acc);
    }
    partial[tid] = acc;
    __syncthreads();
    if (tid < 256) {
        float v = partial[d] + partial[d + 256] + partial[d + 512] + partial[d + 768];
        if (r == 100) v += b_combine[d];
        g_tabs[(size_t)r * Ddim + d] = v;
    }
}

__device__ __forceinline__ float4 ld4(const float* p) {
    return *reinterpret_cast<const float4*>(p);
}
__device__ __forceinline__ void add4(float4& a, const float4 b) {
    a.x += b.x; a.y += b.y; a.z += b.z; a.w += b.w;
}
__device__ __forceinline__ void fma4(float4& a, const float s, const float4 b) {
    a.x = fmaf(s, b.x, a.x);
    a.y = fmaf(s, b.y, a.y);
    a.z = fmaf(s, b.z, a.z);
    a.w = fmaf(s, b.w, a.w);
}

// One wave (64 lanes) per event; lane holds d = 4*lane .. 4*lane+3 as float4.
// 4 waves per 256-thread block -> grid = 8192/4 = 2048 blocks.
__global__ __launch_bounds__(256) void event_embed(
    const int* __restrict__ card_ids,
    const int* __restrict__ hero_pos,
    const int* __restrict__ acting_pos,
    const int* __restrict__ num_players,
    const int* __restrict__ seq_lengths,
    const float* __restrict__ scalars,
    const float* __restrict__ bets,
    const float* __restrict__ action,
    const float* __restrict__ source_table,
    const float* __restrict__ ln_gamma,
    const float* __restrict__ ln_beta,
    float* __restrict__ out_emb,
    float* __restrict__ out_mask)
{
    const int wave = threadIdx.x >> 6;
    const int lane = threadIdx.x & 63;
    const int g = (blockIdx.x << 2) + wave;   // event index in [0, B*E)
    const int b = g >> 8;                     // E = 256
    const int e = g & 255;
    const int d0 = lane << 2;

    const float* cardP = g_tabs;
    const float* heroP = cardP + 53 * Ddim;
    const float* actP  = heroP +  9 * Ddim;
    const float* numP  = actP  +  9 * Ddim;
    const float* WsP   = numP  + 10 * Ddim;
    const float* WbP   = WsP   +  2 * Ddim;
    const float* WaP   = WbP   +  9 * Ddim;
    const float* bP    = WaP   +  8 * Ddim;

    const float maskf = (e < seq_lengths[b]) ? 1.0f : 0.0f;

    // context vector shared by the event's 7 cards
    float4 ctx = ld4(bP + d0);
    add4(ctx, ld4(heroP + (size_t)hero_pos[g]    * Ddim + d0));
    add4(ctx, ld4(actP  + (size_t)acting_pos[g]  * Ddim + d0));
    add4(ctx, ld4(numP  + (size_t)num_players[g] * Ddim + d0));
    fma4(ctx, scalars[(size_t)g * 2 + 0], ld4(WsP + d0));
    fma4(ctx, scalars[(size_t)g * 2 + 1], ld4(WsP + Ddim + d0));
    #pragma unroll
    for (int j = 0; j < 9; ++j)
        fma4(ctx, bets[(size_t)g * 9 + j], ld4(WbP + j * Ddim + d0));
    #pragma unroll
    for (int j = 0; j < 8; ++j)
        fma4(ctx, action[(size_t)g * 8 + j], ld4(WaP + j * Ddim + d0));

    const float4 gam = ld4(ln_gamma + d0);
    const float4 bta = ld4(ln_beta + d0);
    const float4 s0v = ld4(source_table + d0);          // source id 0 (cards 0..4)
    const float4 s1v = ld4(source_table + Ddim + d0);   // source id 1 (cards 5..6)

    #pragma unroll
    for (int c = 0; c < Cdim; ++c) {
        const int cid = card_ids[(size_t)g * Cdim + c];
        float4 h = ld4(cardP + (size_t)cid * Ddim + d0);
        add4(h, ctx);

        float s  = h.x + h.y + h.z + h.w;
        float sq = h.x * h.x + h.y * h.y + h.z * h.z + h.w * h.w;
        #pragma unroll
        for (int off = 32; off > 0; off >>= 1) {
            s  += __shfl_xor(s,  off, 64);
            sq += __shfl_xor(sq, off, 64);
        }
        const float mean = s * (1.0f / 256.0f);
        const float var  = fmaf(-mean, mean, sq * (1.0f / 256.0f));
        const float inv  = rsqrtf(var + 1e-5f);

        const float4 sv = (c < 5) ? s0v : s1v;
        float4 o;
        o.x = (fmaf((h.x - mean) * inv, gam.x, bta.x) + sv.x) * maskf;
        o.y = (fmaf((h.y - mean) * inv, gam.y, bta.y) + sv.y) * maskf;
        o.z = (fmaf((h.z - mean) * inv, gam.z, bta.z) + sv.z) * maskf;
        o.w = (fmaf((h.w - mean) * inv, gam.w, bta.w) + sv.w) * maskf;
        *reinterpret_cast<float4*>(out_emb + ((size_t)g * Cdim + c) * Ddim + d0) = o;
    }

    if (lane < Cdim)
        out_mask[(size_t)g * Cdim + lane] = maskf;
}

extern "C" void kernel_launch(void* const* d_in, const int* in_sizes, int n_in,
                              void* d_out, int out_size, void* d_ws, size_t ws_size,
                              hipStream_t stream)
{
    (void)in_sizes; (void)n_in; (void)d_ws; (void)ws_size; (void)out_size;

    const int*   card_ids    = (const int*)d_in[0];
    const int*   hero_pos    = (const int*)d_in[1];
    const int*   acting_pos  = (const int*)d_in[2];
    const int*   num_players = (const int*)d_in[3];
    const int*   seq_lengths = (const int*)d_in[4];
    const float* scalars     = (const float*)d_in[5];
    const float* bets        = (const float*)d_in[6];
    const float* action      = (const float*)d_in[7];
    const float* card_table  = (const float*)d_in[8];
    const float* source_tab  = (const float*)d_in[9];
    const float* hero_table  = (const float*)d_in[10];
    const float* acting_tab  = (const float*)d_in[11];
    const float* nump_table  = (const float*)d_in[12];
    const float* W_scalar    = (const float*)d_in[13];
    const float* b_scalar    = (const float*)d_in[14];
    const float* W_bet       = (const float*)d_in[15];
    const float* b_bet       = (const float*)d_in[16];
    const float* W_action    = (const float*)d_in[17];
    const float* b_action    = (const float*)d_in[18];
    const float* W_combine   = (const float*)d_in[19];
    const float* b_combine   = (const float*)d_in[20];
    const float* ln_gamma    = (const float*)d_in[21];
    const float* ln_beta     = (const float*)d_in[22];

    float* out_emb  = (float*)d_out;
    float* out_mask = out_emb + (size_t)Bdim * Edim * Cdim * Ddim;

    hipLaunchKernelGGL(precompute_tables, dim3(101), dim3(1024), 0, stream,
                       card_table, hero_table, acting_tab, nump_table,
                       W_scalar, b_scalar, W_bet, b_bet, W_action, b_action,
                       W_combine, b_combine);

    const int nEvents = Bdim * Edim;             // 8192
    hipLaunchKernelGGL(event_embed, dim3(nEvents / 4), dim3(256), 0, stream,
                       card_ids, hero_pos, acting_pos, num_players, seq_lengths,
                       scalars, bets, action, source_tab, ln_gamma, ln_beta,
                       out_emb, out_mask);
}